// Round 1
// baseline (98.952 us; speedup 1.0000x reference)
//
#include <hip/hip_runtime.h>
#include <hip/hip_bf16.h>

// out[b,n] = sum_h x[b,h] * mask[b,n,h]
// B=8, N_PARCELS=256, HW=65536. One block per (b,n) pair.
// mask row is contiguous (hw innermost) -> fully coalesced float4 streaming.
// x row (256 KB/batch, 2 MB total) is reused by 256 blocks -> L2-resident.

#define HW      65536
#define HW4     (HW / 4)      // 16384 float4 per row
#define NPARC   256
#define BLOCK   256

__global__ __launch_bounds__(BLOCK) void
regionAgg_kernel(const float* __restrict__ x,
                 const float* __restrict__ mask,
                 float* __restrict__ out) {
    const int bn = blockIdx.x;            // 0 .. B*NPARC-1
    const int b  = bn >> 8;               // bn / NPARC

    const float4* __restrict__ xv = reinterpret_cast<const float4*>(x    + (size_t)b  * HW);
    const float4* __restrict__ mv = reinterpret_cast<const float4*>(mask + (size_t)bn * HW);

    float acc = 0.0f;
    // 16384 float4 / 256 threads = 64 iterations, stride-BLOCK coalesced
    #pragma unroll 4
    for (int i = threadIdx.x; i < HW4; i += BLOCK) {
        float4 xa = xv[i];
        float4 ma = mv[i];
        acc += xa.x * ma.x + xa.y * ma.y + xa.z * ma.z + xa.w * ma.w;
    }

    // wave-64 butterfly reduce
    #pragma unroll
    for (int off = 32; off > 0; off >>= 1)
        acc += __shfl_down(acc, off, 64);

    __shared__ float s[BLOCK / 64];
    const int lane = threadIdx.x & 63;
    const int wid  = threadIdx.x >> 6;
    if (lane == 0) s[wid] = acc;
    __syncthreads();
    if (threadIdx.x == 0)
        out[bn] = s[0] + s[1] + s[2] + s[3];
}

extern "C" void kernel_launch(void* const* d_in, const int* in_sizes, int n_in,
                              void* d_out, int out_size, void* d_ws, size_t ws_size,
                              hipStream_t stream) {
    const float* x    = (const float*)d_in[0];   // [8, 65536]
    const float* mask = (const float*)d_in[1];   // [8, 256, 65536]
    float* out        = (float*)d_out;           // [8, 256]

    const int nblocks = 8 * NPARC;               // 2048
    regionAgg_kernel<<<nblocks, BLOCK, 0, stream>>>(x, mask, out);
}

// Round 3
// 93.558 us; speedup vs baseline: 1.0577x; 1.0577x over previous
//
#include <hip/hip_runtime.h>
#include <hip/hip_bf16.h>

// out[b,n] = sum_h x[b,h] * mask[b,n,h]
// B=8, N_PARCELS=256, HW=65536. One block per (b,n) pair.
// mask: 512 MB zero-reuse stream -> nontemporal loads (don't evict x from L2).
// x: 2 MB, reused 256x -> normal cached loads, stays L2-resident.

#define HW      65536
#define HW4     (HW / 4)      // 16384 float4 per row
#define NPARC   256
#define BLOCK   256

typedef float f32x4 __attribute__((ext_vector_type(4)));

__global__ __launch_bounds__(BLOCK) void
regionAgg_kernel(const float* __restrict__ x,
                 const float* __restrict__ mask,
                 float* __restrict__ out) {
    const int bn = blockIdx.x;            // 0 .. B*NPARC-1
    const int b  = bn >> 8;               // bn / NPARC

    const f32x4* __restrict__ xv = reinterpret_cast<const f32x4*>(x    + (size_t)b  * HW);
    const f32x4* __restrict__ mv = reinterpret_cast<const f32x4*>(mask + (size_t)bn * HW);

    float acc0 = 0.0f, acc1 = 0.0f, acc2 = 0.0f, acc3 = 0.0f;
    // 16384 float4 / (256 threads * 4-way unroll) = 16 iterations
    for (int i = threadIdx.x; i < HW4; i += BLOCK * 4) {
        f32x4 m0 = __builtin_nontemporal_load(&mv[i]);
        f32x4 m1 = __builtin_nontemporal_load(&mv[i + BLOCK]);
        f32x4 m2 = __builtin_nontemporal_load(&mv[i + 2 * BLOCK]);
        f32x4 m3 = __builtin_nontemporal_load(&mv[i + 3 * BLOCK]);
        f32x4 x0 = xv[i];
        f32x4 x1 = xv[i + BLOCK];
        f32x4 x2 = xv[i + 2 * BLOCK];
        f32x4 x3 = xv[i + 3 * BLOCK];
        acc0 += x0.x * m0.x + x0.y * m0.y + x0.z * m0.z + x0.w * m0.w;
        acc1 += x1.x * m1.x + x1.y * m1.y + x1.z * m1.z + x1.w * m1.w;
        acc2 += x2.x * m2.x + x2.y * m2.y + x2.z * m2.z + x2.w * m2.w;
        acc3 += x3.x * m3.x + x3.y * m3.y + x3.z * m3.z + x3.w * m3.w;
    }
    float acc = (acc0 + acc1) + (acc2 + acc3);

    // wave-64 butterfly reduce
    #pragma unroll
    for (int off = 32; off > 0; off >>= 1)
        acc += __shfl_down(acc, off, 64);

    __shared__ float s[BLOCK / 64];
    const int lane = threadIdx.x & 63;
    const int wid  = threadIdx.x >> 6;
    if (lane == 0) s[wid] = acc;
    __syncthreads();
    if (threadIdx.x == 0)
        out[bn] = s[0] + s[1] + s[2] + s[3];
}

extern "C" void kernel_launch(void* const* d_in, const int* in_sizes, int n_in,
                              void* d_out, int out_size, void* d_ws, size_t ws_size,
                              hipStream_t stream) {
    const float* x    = (const float*)d_in[0];   // [8, 65536]
    const float* mask = (const float*)d_in[1];   // [8, 256, 65536]
    float* out        = (float*)d_out;           // [8, 256]

    const int nblocks = 8 * NPARC;               // 2048
    regionAgg_kernel<<<nblocks, BLOCK, 0, stream>>>(x, mask, out);
}

// Round 4
// 92.652 us; speedup vs baseline: 1.0680x; 1.0098x over previous
//
#include <hip/hip_runtime.h>
#include <hip/hip_bf16.h>

// out[b,n] = sum_h x[b,h] * mask[b,n,h]
// B=8, N_PARCELS=256, HW=65536.
// Two blocks per (b,n) row (half-row each) -> 4096 blocks, finer tail quantum.
// mask: 512 MB zero-reuse stream -> nontemporal loads (don't evict x from L2).
// x: 2 MB, reused 256x -> normal cached loads, stays L2-resident.
// Partial sums from the two half-row blocks combine via atomicAdd into d_out
// (harness zeroes d_out before each timed call? NO -- it poisons once).
// => can't atomicAdd into d_out without re-zeroing. Instead: each block owns
// a distinct output... simplest correct scheme: block pair (lo/hi half) both
// compute partials; block writes partial to ws, second pass tiny kernel sums.
// Cheaper: keep ONE block per row but split the row between its 4 waves more
// finely is already the case. -> Use non-atomic scheme: 4096 blocks write
// 4096 partials to d_ws, then a 2048-thread finisher kernel sums pairs.

#define HW      65536
#define HW4     (HW / 4)      // 16384 float4 per row
#define HALF4   (HW4 / 2)     // 8192 float4 per half-row
#define NPARC   256
#define BLOCK   256

typedef float f32x4 __attribute__((ext_vector_type(4)));

__global__ __launch_bounds__(BLOCK) void
regionAgg_partial(const float* __restrict__ x,
                  const float* __restrict__ mask,
                  float* __restrict__ partial) {
    const int blk  = blockIdx.x;          // 0 .. 2*B*NPARC-1
    const int bn   = blk >> 1;            // row index
    const int half = blk & 1;
    const int b    = bn >> 8;

    const f32x4* __restrict__ xv = reinterpret_cast<const f32x4*>(x    + (size_t)b  * HW) + half * HALF4;
    const f32x4* __restrict__ mv = reinterpret_cast<const f32x4*>(mask + (size_t)bn * HW) + half * HALF4;

    float acc0 = 0.0f, acc1 = 0.0f, acc2 = 0.0f, acc3 = 0.0f;
    // 8192 float4 / (256 threads * 4-way unroll) = 8 iterations
    #pragma clang loop unroll_count(2)
    for (int i = threadIdx.x; i < HALF4; i += BLOCK * 4) {
        f32x4 m0 = __builtin_nontemporal_load(&mv[i]);
        f32x4 m1 = __builtin_nontemporal_load(&mv[i + BLOCK]);
        f32x4 m2 = __builtin_nontemporal_load(&mv[i + 2 * BLOCK]);
        f32x4 m3 = __builtin_nontemporal_load(&mv[i + 3 * BLOCK]);
        f32x4 x0 = xv[i];
        f32x4 x1 = xv[i + BLOCK];
        f32x4 x2 = xv[i + 2 * BLOCK];
        f32x4 x3 = xv[i + 3 * BLOCK];
        acc0 += x0.x * m0.x + x0.y * m0.y + x0.z * m0.z + x0.w * m0.w;
        acc1 += x1.x * m1.x + x1.y * m1.y + x1.z * m1.z + x1.w * m1.w;
        acc2 += x2.x * m2.x + x2.y * m2.y + x2.z * m2.z + x2.w * m2.w;
        acc3 += x3.x * m3.x + x3.y * m3.y + x3.z * m3.z + x3.w * m3.w;
    }
    float acc = (acc0 + acc1) + (acc2 + acc3);

    // wave-64 butterfly reduce
    #pragma unroll
    for (int off = 32; off > 0; off >>= 1)
        acc += __shfl_down(acc, off, 64);

    __shared__ float s[BLOCK / 64];
    const int lane = threadIdx.x & 63;
    const int wid  = threadIdx.x >> 6;
    if (lane == 0) s[wid] = acc;
    __syncthreads();
    if (threadIdx.x == 0)
        partial[blk] = s[0] + s[1] + s[2] + s[3];
}

__global__ __launch_bounds__(256) void
regionAgg_finish(const float* __restrict__ partial, float* __restrict__ out, int n) {
    int i = blockIdx.x * 256 + threadIdx.x;
    if (i < n)
        out[i] = partial[2 * i] + partial[2 * i + 1];
}

extern "C" void kernel_launch(void* const* d_in, const int* in_sizes, int n_in,
                              void* d_out, int out_size, void* d_ws, size_t ws_size,
                              hipStream_t stream) {
    const float* x    = (const float*)d_in[0];   // [8, 65536]
    const float* mask = (const float*)d_in[1];   // [8, 256, 65536]
    float* out        = (float*)d_out;           // [8, 256]
    float* partial    = (float*)d_ws;            // 4096 floats

    const int nrows = 8 * NPARC;                 // 2048
    regionAgg_partial<<<2 * nrows, BLOCK, 0, stream>>>(x, mask, partial);
    regionAgg_finish<<<(nrows + 255) / 256, 256, 0, stream>>>(partial, out, nrows);
}